// Round 4
// baseline (548.205 us; speedup 1.0000x reference)
//
#include <hip/hip_runtime.h>
#include <math.h>

#define BSZ 4
#define DD 48
#define SS (48*48*48)          // 110592 spatial per (b, channel)
#define NV (BSZ*SS)            // 442368 voxels per channel over batch
#define PS 125000              // 50^3 padded volume
#define EPSBN 1e-5f

typedef __attribute__((ext_vector_type(8))) short bf16x8;
typedef __attribute__((ext_vector_type(4))) float f32x4;

__device__ __forceinline__ short f2b(float f){           // fp32 -> bf16 bits (RNE)
  unsigned u = __float_as_uint(f);
  u = (u + 0x7FFFu + ((u>>16)&1u)) >> 16;
  return (short)u;
}
__device__ __forceinline__ float b2f(short s){
  return __uint_as_float(((unsigned)(unsigned short)s)<<16);
}

// ---------------- zero-pad copy: (4,48^3) -> (4,50^3) ----------------
__global__ __launch_bounds__(256) void pad_kernel(
    const float* __restrict__ src, float* __restrict__ dst)
{
  int idx = blockIdx.x*256 + threadIdx.x;
  if (idx >= BSZ*PS) return;
  int b = idx / PS; int r = idx - b*PS;
  int z = r/2500; int r2 = r - z*2500; int yy = r2/50; int xx = r2 - yy*50;
  float v = 0.f;
  if (z>=1 && z<=48 && yy>=1 && yy<=48 && xx>=1 && xx<=48)
    v = src[(size_t)b*SS + (size_t)((z-1)*48 + (yy-1))*48 + (xx-1)];
  dst[idx] = v;
}

// ---------------- offset/mask weight repack: wo[112][32] bf16 ----------------
// rows 0..80 = w_p, rows 81..107 = w_m, rest/taps>=27 = 0 (hard zeros!)
__global__ void woff_kernel(const float* __restrict__ w_p,
                            const float* __restrict__ w_m, short* __restrict__ wo)
{
  int o = blockIdx.x*256 + threadIdx.x;
  if (o >= 112*32) return;
  int tap = o & 31; int co = o >> 5;
  float v = 0.f;
  if (tap < 27){
    if (co < 81)       v = w_p[co*27 + tap];
    else if (co < 108) v = w_m[(co-81)*27 + tap];
  }
  wo[o] = f2b(v);
}

// ---------------- deformable conv stage: MFMA offset-conv + sampler ----------
// Block: 256 threads = 4 waves, tile 4(d) x 4(h) x 16(w) voxels.
// Phase 1: im2col MFMA computes 108 offset/mask channels -> om LDS (bf16).
// Phase 2: one thread per voxel samples trilinear from padded x, writes y.
// Phase 3 (WRITE_P): coalesced p dump from om + bias.
template<bool WRITE_P>
__global__ __launch_bounds__(256) void deform2_kernel(
    const float* __restrict__ xpad,       // (4,50^3) padded stage input
    const short* __restrict__ wo,         // [112][32] bf16
    const float* __restrict__ b_p, const float* __restrict__ b_m,
    const float* __restrict__ w_dc,
    float* __restrict__ y, float* __restrict__ p_out)
{
  __shared__ short om[256*116];                       // 59392 B offset/mask channels
  __shared__ short xt[6*6*18];                        // 2592 B input halo (bf16)
  __shared__ int s_lutc[WRITE_P ? 81 : 1];
  __shared__ int s_lutd[WRITE_P ? 81 : 1];

  int bid = blockIdx.x;
  int bw = bid % 3; int bh = (bid/3)%12; int bd = (bid/36)%12; int b = bid/432;
  int d0 = bd*4, h0 = bh*4, w0 = bw*16;
  int tid = threadIdx.x;
  const float* xp = xpad + (size_t)b*PS;

  // stage halo from padded x (coords always in range)
  for (int e = tid; e < 648; e += 256){
    int z = e/108; int rem = e - z*108; int yy = rem/18; int xx = rem - yy*18;
    xt[e] = f2b(xp[(d0+z)*2500 + (h0+yy)*50 + (w0+xx)]);
  }
  if (WRITE_P && tid < 81){
    int comp = tid/27; int tap = tid - comp*27;
    int kd = tap/9; int rr = tap - kd*9; int kh = rr/3; int kw = rr - kh*3;
    s_lutc[tid] = comp;
    s_lutd[tid] = (comp==0)?kd:((comp==1)?kh:kw);
  }
  __syncthreads();

  int lane = tid & 63, wid = tid >> 6;
  int q = lane >> 4, n16 = lane & 15;

  // A frags: 7 x 16 couts, contiguous bf16x8 per lane
  bf16x8 aF[7];
  #pragma unroll
  for (int f=0; f<7; ++f)
    aF[f] = *(const bf16x8*)(wo + (f*16 + n16)*32 + q*8);

  // per-lane tap LDS offsets (taps q*8+j, clamped to 26; A cols >=27 are zero)
  int off0,off1,off2,off3,off4,off5,off6,off7;
  {
    int t, kd, rr, kh, kw;
    #define MKOFF(J, DST) { t = q*8+(J); t = t>26?26:t; kd=t/9; rr=t-kd*9; kh=rr/3; kw=rr-kh*3; DST = kd*108+kh*18+kw; }
    MKOFF(0,off0) MKOFF(1,off1) MKOFF(2,off2) MKOFF(3,off3)
    MKOFF(4,off4) MKOFF(5,off5) MKOFF(6,off6) MKOFF(7,off7)
    #undef MKOFF
  }

  f32x4 zero4 = {0.f,0.f,0.f,0.f};
  f32x4 acc[7][4];
  #pragma unroll
  for (int f=0; f<7; ++f)
  #pragma unroll
  for (int dy=0; dy<4; ++dy) acc[f][dy] = zero4;

  #pragma unroll
  for (int dy=0; dy<4; ++dy){
    int base = wid*108 + dy*18 + n16;
    bf16x8 bF;
    bF[0]=xt[base+off0]; bF[1]=xt[base+off1]; bF[2]=xt[base+off2]; bF[3]=xt[base+off3];
    bF[4]=xt[base+off4]; bF[5]=xt[base+off5]; bF[6]=xt[base+off6]; bF[7]=xt[base+off7];
    #pragma unroll
    for (int f=0; f<7; ++f)
      acc[f][dy] = __builtin_amdgcn_mfma_f32_16x16x32_bf16(aF[f], bF, acc[f][dy], 0,0,0);
  }

  // acc -> om LDS: row = wid*64 + dy*16 + n16, channel = f*16 + q*4 + r
  #pragma unroll
  for (int f=0; f<7; ++f)
  #pragma unroll
  for (int dy=0; dy<4; ++dy){
    int row = wid*64 + dy*16 + n16;
    unsigned lo = (unsigned)(unsigned short)f2b(acc[f][dy][0]) |
                  ((unsigned)(unsigned short)f2b(acc[f][dy][1]) << 16);
    unsigned hi = (unsigned)(unsigned short)f2b(acc[f][dy][2]) |
                  ((unsigned)(unsigned short)f2b(acc[f][dy][3]) << 16);
    unsigned* dst = (unsigned*)&om[row*116 + f*16 + q*4];
    dst[0] = lo; dst[1] = hi;
  }

  // ---- phase 2: sampler, one thread per voxel (same-wave om rows) ----
  {
    int dz = tid>>6, dyy = (tid>>4)&3, ww = tid&15;
    int dgl = d0+dz, hgl = h0+dyy, wgl = w0+ww;
    const short* myom = om + tid*116;
    float accv = 0.f;
    int kd=0, kh=0, kw=0;
    #pragma unroll 1
    for (int n=0; n<27; ++n){
      float od = b2f(myom[n])      + b_p[n];
      float oh = b2f(myom[27+n])   + b_p[27+n];
      float ow = b2f(myom[54+n])   + b_p[54+n];
      float mr = b2f(myom[81+n])   + b_m[n];
      float mm = 1.f/(1.f + expf(-mr));
      float pdv = (float)(dgl+kd) + od;
      float phv = (float)(hgl+kh) + oh;
      float pwv = (float)(wgl+kw) + ow;
      float fd0 = fminf(fmaxf(floorf(pdv),0.f),49.f), fd1 = fminf(fd0+1.f,49.f);
      float pdc = fminf(fmaxf(pdv,0.f),49.f);
      float wd0 = 1.f + fd0 - pdc, wd1 = 1.f - fd1 + pdc;
      float fh0 = fminf(fmaxf(floorf(phv),0.f),49.f), fh1 = fminf(fh0+1.f,49.f);
      float phc = fminf(fmaxf(phv,0.f),49.f);
      float wh0 = 1.f + fh0 - phc, wh1 = 1.f - fh1 + phc;
      float fw0 = fminf(fmaxf(floorf(pwv),0.f),49.f), fw1 = fminf(fw0+1.f,49.f);
      float pwc = fminf(fmaxf(pwv,0.f),49.f);
      float wwa = 1.f + fw0 - pwc, wwb = 1.f - fw1 + pwc;
      int iz0 = (int)fd0*2500, iz1 = (int)fd1*2500;
      int iy0 = (int)fh0*50,   iy1 = (int)fh1*50;
      int ix0 = (int)fw0,      ix1 = (int)fw1;
      float v000=xp[iz0+iy0+ix0], v001=xp[iz0+iy0+ix1];
      float v010=xp[iz0+iy1+ix0], v011=xp[iz0+iy1+ix1];
      float v100=xp[iz1+iy0+ix0], v101=xp[iz1+iy0+ix1];
      float v110=xp[iz1+iy1+ix0], v111=xp[iz1+iy1+ix1];
      float sv = wd0*(wh0*(wwa*v000+wwb*v001)+wh1*(wwa*v010+wwb*v011))
               + wd1*(wh0*(wwa*v100+wwb*v101)+wh1*(wwa*v110+wwb*v111));
      accv += sv*mm*w_dc[n];
      if (++kw == 3){ kw=0; if (++kh==3){ kh=0; ++kd; } }
    }
    y[(size_t)b*SS + (size_t)(dgl*48 + hgl)*48 + wgl] = accv;
  }

  // ---- phase 3: coalesced p dump ----
  if constexpr (WRITE_P){
    __syncthreads();   // om rows of all waves needed below
    #pragma unroll 1
    for (int seg=0; seg<16; ++seg){
      int dz2 = seg>>2, dy2 = seg&3;
      size_t segbase = ((((size_t)b*48 + (d0+dz2))*48 + (h0+dy2))*48 + w0)*81;
      #pragma unroll 1
      for (int m = tid; m < 1296; m += 256){
        int t = m/81; int o = m - t*81;
        float off = b2f(om[(dz2*64 + dy2*16 + t)*116 + o]) + b_p[o];
        int comp = s_lutc[o]; int del = s_lutd[o];
        int basei = (comp==0) ? (d0+dz2+del) : ((comp==1) ? (h0+dy2+del) : (w0+t+del));
        p_out[segbase + m] = fminf(fmaxf((float)basei + off, 0.f), 49.f);
      }
    }
  }
}

// ---------------- BN stats fp32 (deform stages, nch=1) ----------------
__global__ __launch_bounds__(256) void bn_stats_kernel(
    const float* __restrict__ x, int nch, float* __restrict__ sums)
{
  int c = blockIdx.y;
  float s1=0.f, s2=0.f;
  for (int i=blockIdx.x*blockDim.x+threadIdx.x; i<NV; i+=gridDim.x*blockDim.x){
    int b=i/SS; int s=i-b*SS;
    float v = x[((size_t)b*nch+c)*SS + s];
    s1+=v; s2+=v*v;
  }
  __shared__ float r1[256], r2[256];
  r1[threadIdx.x]=s1; r2[threadIdx.x]=s2; __syncthreads();
  for (int o=128;o>0;o>>=1){
    if (threadIdx.x<o){ r1[threadIdx.x]+=r1[threadIdx.x+o]; r2[threadIdx.x]+=r2[threadIdx.x+o]; }
    __syncthreads();
  }
  if (threadIdx.x==0){ atomicAdd(&sums[2*c],r1[0]); atomicAdd(&sums[2*c+1],r2[0]); }
}

// ---------------- BN normalize + relu fp32 (deform stages) ----------------
__global__ __launch_bounds__(256) void bn_relu_kernel(
    const float* __restrict__ x, float* __restrict__ out,
    const float* __restrict__ sums, const float* __restrict__ gamma,
    const float* __restrict__ beta, int nch)
{
  size_t idx = (size_t)blockIdx.x*blockDim.x + threadIdx.x;
  size_t total = (size_t)BSZ*nch*SS;
  if (idx>=total) return;
  int c = (int)((idx/SS)%nch);
  float mu  = sums[2*c]  *(1.f/(float)NV);
  float var = sums[2*c+1]*(1.f/(float)NV) - mu*mu;
  float v = (x[idx]-mu)*rsqrtf(var+EPSBN)*gamma[c]+beta[c];
  out[idx] = fmaxf(v,0.f);
}

// ---------------- BN stats over bf16 tensor ----------------
__global__ __launch_bounds__(256) void bn_stats_bf16(
    const short* __restrict__ x, int nch, float* __restrict__ sums)
{
  int c = blockIdx.y;
  const int S8 = SS/8;
  float s1=0.f, s2=0.f;
  for (int i8=blockIdx.x*blockDim.x+threadIdx.x; i8<BSZ*S8; i8+=gridDim.x*blockDim.x){
    int b=i8/S8; int s8=i8-b*S8;
    const bf16x8 v8 = *(const bf16x8*)(x + ((size_t)b*nch+c)*SS + (size_t)s8*8);
    #pragma unroll
    for (int j=0;j<8;++j){ float v=b2f(v8[j]); s1+=v; s2+=v*v; }
  }
  __shared__ float r1[256], r2[256];
  r1[threadIdx.x]=s1; r2[threadIdx.x]=s2; __syncthreads();
  for (int o=128;o>0;o>>=1){
    if (threadIdx.x<o){ r1[threadIdx.x]+=r1[threadIdx.x+o]; r2[threadIdx.x]+=r2[threadIdx.x+o]; }
    __syncthreads();
  }
  if (threadIdx.x==0){ atomicAdd(&sums[2*c],r1[0]); atomicAdd(&sums[2*c+1],r2[0]); }
}

// ---------------- BN + relu in place over bf16 tensor ----------------
__global__ __launch_bounds__(256) void bn_relu_bf16(
    short* __restrict__ x, const float* __restrict__ sums,
    const float* __restrict__ gamma, const float* __restrict__ beta, int nch)
{
  const int S8 = SS/8;
  size_t i8 = (size_t)blockIdx.x*blockDim.x + threadIdx.x;
  size_t total8 = (size_t)BSZ*nch*S8;
  if (i8>=total8) return;
  int c = (int)((i8/S8)%nch);
  float mu  = sums[2*c]  *(1.f/(float)NV);
  float var = sums[2*c+1]*(1.f/(float)NV) - mu*mu;
  float sc = rsqrtf(var+EPSBN)*gamma[c];
  float sh = beta[c] - mu*sc;
  bf16x8 v8 = *(bf16x8*)(x + i8*8);
  #pragma unroll
  for (int j=0;j<8;++j){
    float v = fmaxf(fmaf(b2f(v8[j]),sc,sh),0.f);
    v8[j] = f2b(v);
  }
  *(bf16x8*)(x + i8*8) = v8;
}

// ---------------- conv1: 1 -> 32 channels, fp32 in, bf16 out ----------------
__global__ __launch_bounds__(256) void conv1_kernel(
    const float* __restrict__ x, const float* __restrict__ wt, short* __restrict__ out)
{
  __shared__ float sw[32*27];
  for (int i=threadIdx.x;i<32*27;i+=blockDim.x) sw[i]=wt[i];
  __syncthreads();
  int idx = blockIdx.x*blockDim.x + threadIdx.x;
  if (idx >= NV) return;
  int b = idx / SS; int s = idx - b*SS;
  int d = s / (DD*DD); int r2 = s - d*DD*DD; int h = r2/DD; int w = r2 - h*DD;
  const float* xb = x + (size_t)b*SS;
  float nb[27];
  #pragma unroll
  for (int kd=0;kd<3;++kd)
  #pragma unroll
  for (int kh=0;kh<3;++kh)
  #pragma unroll
  for (int kw=0;kw<3;++kw){
    int zz=d+kd-1, yy=h+kh-1, xx=w+kw-1;
    bool ok = ((unsigned)zz<48u)&&((unsigned)yy<48u)&&((unsigned)xx<48u);
    nb[kd*9+kh*3+kw] = ok ? xb[(zz*48+yy)*48+xx] : 0.f;
  }
  #pragma unroll 1
  for (int c=0;c<32;++c){
    float a=0.f;
    #pragma unroll
    for (int t=0;t<27;++t) a = fmaf(sw[c*27+t], nb[t], a);
    out[((size_t)b*32+c)*SS + s] = f2b(a);
  }
}

// ---------------- conv2 weight repack: (co,ci,tap) fp32 -> (tap,co,ci) bf16 ----
__global__ void wconv_kernel(const float* __restrict__ w, short* __restrict__ wbf)
{
  int o = blockIdx.x*blockDim.x + threadIdx.x;
  if (o >= 27*64*32) return;
  int ci = o & 31; int co = (o>>5) & 63; int tap = o >> 11;
  wbf[o] = f2b(w[(co*32+ci)*27 + tap]);
}

// ---------------- conv2 via MFMA: 32 -> 64 channels, bf16 ----------------
__global__ __launch_bounds__(256) void conv2_mfma(
    const short* __restrict__ h1, const short* __restrict__ wbf,
    short* __restrict__ t2)
{
  __shared__ __align__(16) short slab[6*6*18*32];  // 41472 B
  int bid = blockIdx.x;
  int bw = bid % 3; int bh = (bid/3)%12; int bd = (bid/36)%12; int b = bid/432;
  int d0 = bd*4, h0 = bh*4, w0 = bw*16;
  int tid = threadIdx.x;
  const short* hb = h1 + (size_t)b*32*SS;

  for (int e = tid; e < 648; e += 256){
    int z = e/108; int rem = e - z*108; int y = rem/18; int x = rem - y*18;
    int gd = d0-1+z, gh = h0-1+y, gw = w0-1+x;
    bool ok = ((unsigned)gd<48u)&&((unsigned)gh<48u)&&((unsigned)gw<48u);
    int gbase = ok ? (gd*48+gh)*48+gw : 0;
    int swz = (x&3)<<3;
    int lbase = e*32;
    #pragma unroll
    for (int ci=0; ci<32; ci+=2){
      short v0 = ok ? hb[(size_t)ci*SS + gbase] : (short)0;
      short v1 = ok ? hb[(size_t)(ci+1)*SS + gbase] : (short)0;
      int p0 = ci ^ swz;
      slab[lbase + p0]     = v0;
      slab[lbase + p0 + 1] = v1;
    }
  }
  __syncthreads();

  int lane = tid & 63, wid = tid >> 6;
  int q = lane >> 4, n16 = lane & 15;
  f32x4 zero4 = {0.f,0.f,0.f,0.f};
  f32x4 acc[4][4];
  #pragma unroll
  for (int i=0;i<4;++i)
  #pragma unroll
  for (int j=0;j<4;++j) acc[i][j] = zero4;

  #pragma unroll 1
  for (int tap=0; tap<27; ++tap){
    int kd = tap/9; int kh = (tap/3)%3; int kw = tap%3;
    const short* wp = wbf + (size_t)tap*64*32 + n16*32 + q*8;
    bf16x8 aF[4];
    #pragma unroll
    for (int mb=0; mb<4; ++mb)
      aF[mb] = *(const bf16x8*)(wp + mb*16*32);

    int xx = n16 + kw;
    int cof = (q ^ (xx&3)) << 3;
    int zz = wid + kd;
    bf16x8 bF[4];
    #pragma unroll
    for (int dy=0; dy<4; ++dy){
      int yy = dy + kh;
      bF[dy] = *(const bf16x8*)&slab[ ((zz*6 + yy)*18 + xx)*32 + cof ];
    }
    #pragma unroll
    for (int mb=0; mb<4; ++mb)
      #pragma unroll
      for (int dy=0; dy<4; ++dy)
        acc[mb][dy] = __builtin_amdgcn_mfma_f32_16x16x32_bf16(aF[mb], bF[dy], acc[mb][dy], 0,0,0);
  }

  int d = d0 + wid;
  #pragma unroll
  for (int mb=0; mb<4; ++mb)
  #pragma unroll
  for (int dy=0; dy<4; ++dy){
    int h = h0 + dy, w = w0 + n16;
    #pragma unroll
    for (int r=0; r<4; ++r){
      int c = mb*16 + q*4 + r;
      t2[ (size_t)(b*64+c)*SS + (d*48+h)*48 + w ] = f2b(acc[mb][dy][r]);
    }
  }
}

// ---------------- BN + relu + 3^3/3 maxpool + spatial-sum (bf16 in) ----------
__global__ __launch_bounds__(256) void pool64_kernel(
    const short* __restrict__ t2, const float* __restrict__ sums,
    const float* __restrict__ gamma, const float* __restrict__ beta,
    float* __restrict__ pooled)
{
  int b = blockIdx.z, c = blockIdx.y;
  int cell = blockIdx.x*blockDim.x + threadIdx.x;   // 0..4095
  int pd = cell>>8; int rr = cell&255; int phh = rr>>4; int pww = rr&15;
  float mu  = sums[2*c]  *(1.f/(float)NV);
  float var = sums[2*c+1]*(1.f/(float)NV) - mu*mu;
  float sc  = rsqrtf(var+EPSBN)*gamma[c];
  float sh  = beta[c] - mu*sc;
  const short* base = t2 + ((size_t)b*64+c)*SS;
  float mx = -1e30f;
  #pragma unroll
  for (int kd=0;kd<3;++kd)
  #pragma unroll
  for (int kh=0;kh<3;++kh)
  #pragma unroll
  for (int kw=0;kw<3;++kw){
    float v = b2f(base[((pd*3+kd)*48 + (phh*3+kh))*48 + (pww*3+kw)]);
    v = fmaxf(fmaf(v,sc,sh), 0.f);
    mx = fmaxf(mx, v);
  }
  __shared__ float r[256];
  r[threadIdx.x]=mx; __syncthreads();
  for (int o=128;o>0;o>>=1){
    if (threadIdx.x<o) r[threadIdx.x]+=r[threadIdx.x+o];
    __syncthreads();
  }
  if (threadIdx.x==0) atomicAdd(&pooled[b*64+c], r[0]);
}

// ---------------- FC head ----------------
__global__ void fc_kernel(const float* __restrict__ pooled,
                          const float* __restrict__ w_fc, const float* __restrict__ b_fc,
                          float* __restrict__ logits)
{
  int t = threadIdx.x;
  if (t < 40){
    int b = t/10, k = t - 10*(t/10);
    float a = b_fc[k];
    #pragma unroll 1
    for (int c=0;c<64;++c) a = fmaf(pooled[b*64+c]*(1.f/4096.f), w_fc[k*64+c], a);
    logits[b*10+k] = a;
  }
}

extern "C" void kernel_launch(void* const* d_in, const int* in_sizes, int n_in,
                              void* d_out, int out_size, void* d_ws, size_t ws_size,
                              hipStream_t stream)
{
  const float* x    = (const float*)d_in[0];
  const float* w_p  = (const float*)d_in[1];
  const float* b_p  = (const float*)d_in[2];
  const float* w_m  = (const float*)d_in[3];
  const float* b_m  = (const float*)d_in[4];
  const float* w_dc = (const float*)d_in[5];
  const float* g_d  = (const float*)d_in[6];
  const float* be_d = (const float*)d_in[7];
  const float* w_c1 = (const float*)d_in[8];
  const float* g1   = (const float*)d_in[9];
  const float* be1  = (const float*)d_in[10];
  const float* w_c2 = (const float*)d_in[11];
  const float* g2   = (const float*)d_in[12];
  const float* be2  = (const float*)d_in[13];
  const float* w_fc = (const float*)d_in[14];
  const float* b_fc = (const float*)d_in[15];

  float* out    = (float*)d_out;
  float* logits = out;                 // 40
  float* xxx    = out + 40;            // NV  (stage-2 raw y)
  float* p_out  = out + 40 + NV;       // NV*81

  // workspace layout
  float* ws     = (float*)d_ws;
  float* inp    = ws;                        // NV fp32
  float* stats  = inp + NV;                  // 128
  float* pooled = stats + 128;               // 256
  short* wbf    = (short*)(pooled + 256);    // 27*64*32 bf16
  short* wo     = wbf + 27*64*32;            // 112*32 bf16
  float* xpad   = (float*)(wo + 112*32);     // 4*50^3 fp32
  short* h1bf   = (short*)(xpad + (size_t)BSZ*PS);   // 4*32*SS bf16
  short* t2bf   = h1bf + (size_t)4*32*SS;    // 4*64*SS bf16
  float* y1     = (float*)t2bf;              // NV fp32, aliases t2bf (dead before conv2)

  const int nblk = (NV + 255)/256;     // 1728
  const int pblk = (BSZ*PS + 255)/256;

  // weight repacks (independent)
  wconv_kernel<<<(27*64*32+255)/256,256,0,stream>>>(w_c2, wbf);
  woff_kernel<<<(112*32+255)/256,256,0,stream>>>(w_p, w_m, wo);

  // ---- deform stage 1 ----
  pad_kernel<<<pblk,256,0,stream>>>(x, xpad);
  deform2_kernel<false><<<1728,256,0,stream>>>(xpad, wo, b_p, b_m, w_dc, y1, nullptr);
  hipMemsetAsync(stats, 0, 2*sizeof(float), stream);
  bn_stats_kernel<<<dim3(64,1),256,0,stream>>>(y1, 1, stats);
  bn_relu_kernel<<<nblk,256,0,stream>>>(y1, inp, stats, g_d, be_d, 1);

  // ---- deform stage 2 (writes xxx and p) ----
  pad_kernel<<<pblk,256,0,stream>>>(inp, xpad);
  deform2_kernel<true><<<1728,256,0,stream>>>(xpad, wo, b_p, b_m, w_dc, xxx, p_out);
  hipMemsetAsync(stats, 0, 2*sizeof(float), stream);
  bn_stats_kernel<<<dim3(64,1),256,0,stream>>>(xxx, 1, stats);
  bn_relu_kernel<<<nblk,256,0,stream>>>(xxx, inp, stats, g_d, be_d, 1);

  // ---- conv1 (fp32 in, bf16 out) + BN + relu in place ----
  conv1_kernel<<<nblk,256,0,stream>>>(inp, w_c1, h1bf);
  hipMemsetAsync(stats, 0, 64*sizeof(float), stream);
  bn_stats_bf16<<<dim3(64,32),256,0,stream>>>(h1bf, 32, stats);
  {
    int nb8 = (int)(((size_t)BSZ*32*(SS/8) + 255)/256);
    bn_relu_bf16<<<nb8,256,0,stream>>>(h1bf, stats, g1, be1, 32);
  }

  // ---- conv2 via MFMA (all 64 channels), then BN stats + pool fused ----
  conv2_mfma<<<1728,256,0,stream>>>(h1bf, wbf, t2bf);
  hipMemsetAsync(stats, 0, 128*sizeof(float), stream);
  bn_stats_bf16<<<dim3(64,64),256,0,stream>>>(t2bf, 64, stats);
  hipMemsetAsync(pooled, 0, 256*sizeof(float), stream);
  pool64_kernel<<<dim3(16,64,BSZ),256,0,stream>>>(t2bf, stats, g2, be2, pooled);

  // ---- FC head ----
  fc_kernel<<<1,64,0,stream>>>(pooled, w_fc, b_fc, logits);
}

// Round 5
// 478.469 us; speedup vs baseline: 1.1457x; 1.1457x over previous
//
#include <hip/hip_runtime.h>
#include <math.h>

#define BSZ 4
#define DD 48
#define SS (48*48*48)          // 110592 spatial per (b, channel)
#define NV (BSZ*SS)            // 442368 voxels per channel over batch
#define PS 125000              // 50^3 padded volume
#define EPSBN 1e-5f

typedef __attribute__((ext_vector_type(8))) short bf16x8;
typedef __attribute__((ext_vector_type(4))) float f32x4;

__device__ __forceinline__ short f2b(float f){           // fp32 -> bf16 bits (RNE)
  unsigned u = __float_as_uint(f);
  u = (u + 0x7FFFu + ((u>>16)&1u)) >> 16;
  return (short)u;
}
__device__ __forceinline__ float b2f(short s){
  return __uint_as_float(((unsigned)(unsigned short)s)<<16);
}

// ---------------- zero-pad copy: (4,48^3) -> (4,50^3) ----------------
__global__ __launch_bounds__(256) void pad_kernel(
    const float* __restrict__ src, float* __restrict__ dst)
{
  int idx = blockIdx.x*256 + threadIdx.x;
  if (idx >= BSZ*PS) return;
  int b = idx / PS; int r = idx - b*PS;
  int z = r/2500; int r2 = r - z*2500; int yy = r2/50; int xx = r2 - yy*50;
  float v = 0.f;
  if (z>=1 && z<=48 && yy>=1 && yy<=48 && xx>=1 && xx<=48)
    v = src[(size_t)b*SS + (size_t)((z-1)*48 + (yy-1))*48 + (xx-1)];
  dst[idx] = v;
}

// ---------------- offset/mask weight repack with tap-major channel order ----
// wo2[112][32] bf16. Row c: f=c>>4, q=(c>>2)&3, r=c&3, tap n=4f+q.
//   k<27 : r<3 -> w_p[(r*27+n)*27+k], r==3 -> w_m[n*27+k]
//   k==27: bias column (B supplies 1.0 there): r<3 -> b_p[r*27+n], r==3 -> b_m[n]
//   else 0. Rows with n>=27: all zero.
__global__ void woff2_kernel(const float* __restrict__ w_p, const float* __restrict__ b_p,
                             const float* __restrict__ w_m, const float* __restrict__ b_m,
                             short* __restrict__ wo2)
{
  int o = blockIdx.x*256 + threadIdx.x;
  if (o >= 112*32) return;
  int k = o & 31; int c = o >> 5;
  int f = c >> 4, qq = (c >> 2) & 3, r = c & 3;
  int n = 4*f + qq;
  float v = 0.f;
  if (n < 27){
    if (k < 27)       v = (r < 3) ? w_p[(r*27+n)*27 + k] : w_m[n*27 + k];
    else if (k == 27) v = (r < 3) ? b_p[r*27+n]          : b_m[n];
  }
  wo2[o] = f2b(v);
}

// ---------------- deformable conv stage, transpose-free ----------------
// Block: 256 threads = 4 waves; tile 4(d=wid) x 4(h=dy) x 16(w=n16).
// MFMA with tap-major weights -> lane (q,n16) gets (od,oh,ow,mask) of tap 4f+q
// for voxel (wid,dy,n16) in acc[f]. Sampler is 4-lane cooperative; y via
// shfl-xor reduce. p staged per-dy in LDS whose flat order == output order.
template<bool WRITE_P>
__global__ __launch_bounds__(256) void deform3_kernel(
    const float* __restrict__ xpad,       // (4,50^3) padded stage input
    const short* __restrict__ wo2,        // [112][32] bf16
    const float* __restrict__ w_dc,
    float* __restrict__ y, float* __restrict__ p_out)
{
  __shared__ short xt[6*6*18];                         // 2592 B halo (bf16)
  __shared__ __align__(16) float pbuf[WRITE_P ? 64*81 : 4];  // 20736 B when WRITE_P

  int bid = blockIdx.x;
  int bw = bid % 3; int bh = (bid/3)%12; int bd = (bid/36)%12; int b = bid/432;
  int d0 = bd*4, h0 = bh*4, w0 = bw*16;
  int tid = threadIdx.x;
  const float* xp = xpad + (size_t)b*PS;

  for (int e = tid; e < 648; e += 256){
    int z = e/108; int rem = e - z*108; int yy = rem/18; int xx = rem - yy*18;
    xt[e] = f2b(xp[(d0+z)*2500 + (h0+yy)*50 + (w0+xx)]);
  }
  __syncthreads();

  int lane = tid & 63, wid = tid >> 6;
  int q = lane >> 4, n16 = lane & 15;

  // A frags: rows f*16+n16, K-slots q*8..q*8+7
  bf16x8 aF[7];
  #pragma unroll
  for (int f=0; f<7; ++f)
    aF[f] = *(const bf16x8*)(wo2 + (f*16 + n16)*32 + q*8);

  // per-lane halo offsets for B K-slots t=q*8+j (t>26 -> safe 0, value forced 1.0)
  int toffs[8];
  #pragma unroll
  for (int j=0;j<8;++j){
    int t = q*8 + j; int tc = t > 26 ? 0 : t;
    int kd = tc/9, rr = tc - kd*9, kh = rr/3, kw = rr - kh*3;
    toffs[j] = kd*108 + kh*18 + kw;
  }

  // sampler tap constants for taps n=4f+q
  float wdcv[7], fkd[7], fkh[7], fkw[7];
  #pragma unroll
  for (int f=0; f<7; ++f){
    int n = 4*f + q;
    if (n < 27){
      int kd = n/9, rr = n - kd*9, kh = rr/3, kw = rr - kh*3;
      wdcv[f] = w_dc[n];
      fkd[f] = (float)kd; fkh[f] = (float)kh; fkw[f] = (float)kw;
    } else { wdcv[f]=0.f; fkd[f]=0.f; fkh[f]=0.f; fkw[f]=0.f; }
  }

  const short one_bf = (short)0x3F80;
  const f32x4 zero4 = {0.f,0.f,0.f,0.f};
  float based = (float)(d0 + wid);
  float basew = (float)(w0 + n16);

  #pragma unroll 1
  for (int dy=0; dy<4; ++dy){
    // B frag for this (wid,dy) row of 16 voxels
    int vbase = wid*108 + dy*18 + n16;
    bf16x8 bF;
    #pragma unroll
    for (int j=0;j<8;++j){
      short xv = xt[vbase + toffs[j]];
      bF[j] = (j<3 || q<3) ? xv : one_bf;   // slots t>=27: 1.0 (bias col / zero wt)
    }
    f32x4 acc[7];
    #pragma unroll
    for (int f=0; f<7; ++f)
      acc[f] = __builtin_amdgcn_mfma_f32_16x16x32_bf16(aF[f], bF, zero4, 0,0,0);

    // ---- 4-lane cooperative sampler ----
    float baseh = (float)(h0 + dy);
    float accv = 0.f;
    #pragma unroll
    for (int f=0; f<7; ++f){
      int n = 4*f + q;
      if (n < 27){
        float od = acc[f][0], oh = acc[f][1], ow = acc[f][2], mr = acc[f][3];
        float mm = __builtin_amdgcn_rcpf(1.f + __expf(-mr));
        float pdv = based + fkd[f] + od;
        float phv = baseh + fkh[f] + oh;
        float pwv = basew + fkw[f] + ow;
        float fd0 = fminf(fmaxf(floorf(pdv),0.f),49.f), fd1 = fminf(fd0+1.f,49.f);
        float pdc = fminf(fmaxf(pdv,0.f),49.f);
        float wd0 = 1.f + fd0 - pdc, wd1 = 1.f - fd1 + pdc;
        float fh0 = fminf(fmaxf(floorf(phv),0.f),49.f), fh1 = fminf(fh0+1.f,49.f);
        float phc = fminf(fmaxf(phv,0.f),49.f);
        float wh0 = 1.f + fh0 - phc, wh1 = 1.f - fh1 + phc;
        float fw0 = fminf(fmaxf(floorf(pwv),0.f),49.f), fw1 = fminf(fw0+1.f,49.f);
        float pwc = fminf(fmaxf(pwv,0.f),49.f);
        float wwa = 1.f + fw0 - pwc, wwb = 1.f - fw1 + pwc;
        int iz0 = (int)fd0*2500, iz1 = (int)fd1*2500;
        int iy0 = (int)fh0*50,   iy1 = (int)fh1*50;
        int ix0 = (int)fw0,      ix1 = (int)fw1;
        float v000=xp[iz0+iy0+ix0], v001=xp[iz0+iy0+ix1];
        float v010=xp[iz0+iy1+ix0], v011=xp[iz0+iy1+ix1];
        float v100=xp[iz1+iy0+ix0], v101=xp[iz1+iy0+ix1];
        float v110=xp[iz1+iy1+ix0], v111=xp[iz1+iy1+ix1];
        float sv = wd0*(wh0*(wwa*v000+wwb*v001)+wh1*(wwa*v010+wwb*v011))
                 + wd1*(wh0*(wwa*v100+wwb*v101)+wh1*(wwa*v110+wwb*v111));
        accv += sv*mm*wdcv[f];
        if constexpr (WRITE_P){
          int vb = (wid*16 + n16)*81;
          pbuf[vb + n]      = pdc;
          pbuf[vb + 27 + n] = phc;
          pbuf[vb + 54 + n] = pwc;
        }
      }
    }
    accv += __shfl_xor(accv, 16);
    accv += __shfl_xor(accv, 32);
    if (q == 0)
      y[(size_t)b*SS + (size_t)((d0+wid)*48 + (h0+dy))*48 + (w0+n16)] = accv;

    if constexpr (WRITE_P){
      __syncthreads();                       // all waves' pbuf slices ready
      // wave wid dumps voxels (d0+wid, h0+dy, w0..w0+15): 1296 contiguous floats
      size_t rbase = ((((size_t)b*48 + (d0+wid))*48 + (h0+dy))*48 + w0)*81;
      const float* src = pbuf + wid*1296;
      float* dst = p_out + rbase;
      #pragma unroll
      for (int k=0;k<6;++k){
        int i4 = (lane + (k<<6))<<2;
        if (i4 < 1296){
          f32x4 v = *(const f32x4*)(src + i4);
          *(f32x4*)(dst + i4) = v;
        }
      }
      __syncthreads();                       // before next dy overwrites pbuf
    }
  }
}

// ---------------- BN stats fp32 (deform stages, nch=1) ----------------
__global__ __launch_bounds__(256) void bn_stats_kernel(
    const float* __restrict__ x, int nch, float* __restrict__ sums)
{
  int c = blockIdx.y;
  float s1=0.f, s2=0.f;
  for (int i=blockIdx.x*blockDim.x+threadIdx.x; i<NV; i+=gridDim.x*blockDim.x){
    int b=i/SS; int s=i-b*SS;
    float v = x[((size_t)b*nch+c)*SS + s];
    s1+=v; s2+=v*v;
  }
  __shared__ float r1[256], r2[256];
  r1[threadIdx.x]=s1; r2[threadIdx.x]=s2; __syncthreads();
  for (int o=128;o>0;o>>=1){
    if (threadIdx.x<o){ r1[threadIdx.x]+=r1[threadIdx.x+o]; r2[threadIdx.x]+=r2[threadIdx.x+o]; }
    __syncthreads();
  }
  if (threadIdx.x==0){ atomicAdd(&sums[2*c],r1[0]); atomicAdd(&sums[2*c+1],r2[0]); }
}

// ---------------- BN normalize + relu fp32 (deform stages) ----------------
__global__ __launch_bounds__(256) void bn_relu_kernel(
    const float* __restrict__ x, float* __restrict__ out,
    const float* __restrict__ sums, const float* __restrict__ gamma,
    const float* __restrict__ beta, int nch)
{
  size_t idx = (size_t)blockIdx.x*blockDim.x + threadIdx.x;
  size_t total = (size_t)BSZ*nch*SS;
  if (idx>=total) return;
  int c = (int)((idx/SS)%nch);
  float mu  = sums[2*c]  *(1.f/(float)NV);
  float var = sums[2*c+1]*(1.f/(float)NV) - mu*mu;
  float v = (x[idx]-mu)*rsqrtf(var+EPSBN)*gamma[c]+beta[c];
  out[idx] = fmaxf(v,0.f);
}

// ---------------- BN stats over bf16 tensor ----------------
__global__ __launch_bounds__(256) void bn_stats_bf16(
    const short* __restrict__ x, int nch, float* __restrict__ sums)
{
  int c = blockIdx.y;
  const int S8 = SS/8;
  float s1=0.f, s2=0.f;
  for (int i8=blockIdx.x*blockDim.x+threadIdx.x; i8<BSZ*S8; i8+=gridDim.x*blockDim.x){
    int b=i8/S8; int s8=i8-b*S8;
    const bf16x8 v8 = *(const bf16x8*)(x + ((size_t)b*nch+c)*SS + (size_t)s8*8);
    #pragma unroll
    for (int j=0;j<8;++j){ float v=b2f(v8[j]); s1+=v; s2+=v*v; }
  }
  __shared__ float r1[256], r2[256];
  r1[threadIdx.x]=s1; r2[threadIdx.x]=s2; __syncthreads();
  for (int o=128;o>0;o>>=1){
    if (threadIdx.x<o){ r1[threadIdx.x]+=r1[threadIdx.x+o]; r2[threadIdx.x]+=r2[threadIdx.x+o]; }
    __syncthreads();
  }
  if (threadIdx.x==0){ atomicAdd(&sums[2*c],r1[0]); atomicAdd(&sums[2*c+1],r2[0]); }
}

// ---------------- BN + relu in place over bf16 tensor ----------------
__global__ __launch_bounds__(256) void bn_relu_bf16(
    short* __restrict__ x, const float* __restrict__ sums,
    const float* __restrict__ gamma, const float* __restrict__ beta, int nch)
{
  const int S8 = SS/8;
  size_t i8 = (size_t)blockIdx.x*blockDim.x + threadIdx.x;
  size_t total8 = (size_t)BSZ*nch*S8;
  if (i8>=total8) return;
  int c = (int)((i8/S8)%nch);
  float mu  = sums[2*c]  *(1.f/(float)NV);
  float var = sums[2*c+1]*(1.f/(float)NV) - mu*mu;
  float sc = rsqrtf(var+EPSBN)*gamma[c];
  float sh = beta[c] - mu*sc;
  bf16x8 v8 = *(bf16x8*)(x + i8*8);
  #pragma unroll
  for (int j=0;j<8;++j){
    float v = fmaxf(fmaf(b2f(v8[j]),sc,sh),0.f);
    v8[j] = f2b(v);
  }
  *(bf16x8*)(x + i8*8) = v8;
}

// ---------------- conv1: 1 -> 32 channels, fp32 in, bf16 out ----------------
__global__ __launch_bounds__(256) void conv1_kernel(
    const float* __restrict__ x, const float* __restrict__ wt, short* __restrict__ out)
{
  __shared__ float sw[32*27];
  for (int i=threadIdx.x;i<32*27;i+=blockDim.x) sw[i]=wt[i];
  __syncthreads();
  int idx = blockIdx.x*blockDim.x + threadIdx.x;
  if (idx >= NV) return;
  int b = idx / SS; int s = idx - b*SS;
  int d = s / (DD*DD); int r2 = s - d*DD*DD; int h = r2/DD; int w = r2 - h*DD;
  const float* xb = x + (size_t)b*SS;
  float nb[27];
  #pragma unroll
  for (int kd=0;kd<3;++kd)
  #pragma unroll
  for (int kh=0;kh<3;++kh)
  #pragma unroll
  for (int kw=0;kw<3;++kw){
    int zz=d+kd-1, yy=h+kh-1, xx=w+kw-1;
    bool ok = ((unsigned)zz<48u)&&((unsigned)yy<48u)&&((unsigned)xx<48u);
    nb[kd*9+kh*3+kw] = ok ? xb[(zz*48+yy)*48+xx] : 0.f;
  }
  #pragma unroll 1
  for (int c=0;c<32;++c){
    float a=0.f;
    #pragma unroll
    for (int t=0;t<27;++t) a = fmaf(sw[c*27+t], nb[t], a);
    out[((size_t)b*32+c)*SS + s] = f2b(a);
  }
}

// ---------------- conv2 weight repack: (co,ci,tap) fp32 -> (tap,co,ci) bf16 ----
__global__ void wconv_kernel(const float* __restrict__ w, short* __restrict__ wbf)
{
  int o = blockIdx.x*blockDim.x + threadIdx.x;
  if (o >= 27*64*32) return;
  int ci = o & 31; int co = (o>>5) & 63; int tap = o >> 11;
  wbf[o] = f2b(w[(co*32+ci)*27 + tap]);
}

// ---------------- conv2 via MFMA: 32 -> 64 channels, bf16 ----------------
__global__ __launch_bounds__(256) void conv2_mfma(
    const short* __restrict__ h1, const short* __restrict__ wbf,
    short* __restrict__ t2)
{
  __shared__ __align__(16) short slab[6*6*18*32];  // 41472 B
  int bid = blockIdx.x;
  int bw = bid % 3; int bh = (bid/3)%12; int bd = (bid/36)%12; int b = bid/432;
  int d0 = bd*4, h0 = bh*4, w0 = bw*16;
  int tid = threadIdx.x;
  const short* hb = h1 + (size_t)b*32*SS;

  for (int e = tid; e < 648; e += 256){
    int z = e/108; int rem = e - z*108; int y = rem/18; int x = rem - y*18;
    int gd = d0-1+z, gh = h0-1+y, gw = w0-1+x;
    bool ok = ((unsigned)gd<48u)&&((unsigned)gh<48u)&&((unsigned)gw<48u);
    int gbase = ok ? (gd*48+gh)*48+gw : 0;
    int swz = (x&3)<<3;
    int lbase = e*32;
    #pragma unroll
    for (int ci=0; ci<32; ci+=2){
      short v0 = ok ? hb[(size_t)ci*SS + gbase] : (short)0;
      short v1 = ok ? hb[(size_t)(ci+1)*SS + gbase] : (short)0;
      int p0 = ci ^ swz;
      slab[lbase + p0]     = v0;
      slab[lbase + p0 + 1] = v1;
    }
  }
  __syncthreads();

  int lane = tid & 63, wid = tid >> 6;
  int q = lane >> 4, n16 = lane & 15;
  f32x4 zero4 = {0.f,0.f,0.f,0.f};
  f32x4 acc[4][4];
  #pragma unroll
  for (int i=0;i<4;++i)
  #pragma unroll
  for (int j=0;j<4;++j) acc[i][j] = zero4;

  #pragma unroll 1
  for (int tap=0; tap<27; ++tap){
    int kd = tap/9; int kh = (tap/3)%3; int kw = tap%3;
    const short* wp = wbf + (size_t)tap*64*32 + n16*32 + q*8;
    bf16x8 aF[4];
    #pragma unroll
    for (int mb=0; mb<4; ++mb)
      aF[mb] = *(const bf16x8*)(wp + mb*16*32);

    int xx = n16 + kw;
    int cof = (q ^ (xx&3)) << 3;
    int zz = wid + kd;
    bf16x8 bF[4];
    #pragma unroll
    for (int dy=0; dy<4; ++dy){
      int yy = dy + kh;
      bF[dy] = *(const bf16x8*)&slab[ ((zz*6 + yy)*18 + xx)*32 + cof ];
    }
    #pragma unroll
    for (int mb=0; mb<4; ++mb)
      #pragma unroll
      for (int dy=0; dy<4; ++dy)
        acc[mb][dy] = __builtin_amdgcn_mfma_f32_16x16x32_bf16(aF[mb], bF[dy], acc[mb][dy], 0,0,0);
  }

  int d = d0 + wid;
  #pragma unroll
  for (int mb=0; mb<4; ++mb)
  #pragma unroll
  for (int dy=0; dy<4; ++dy){
    int h = h0 + dy, w = w0 + n16;
    #pragma unroll
    for (int r=0; r<4; ++r){
      int c = mb*16 + q*4 + r;
      t2[ (size_t)(b*64+c)*SS + (d*48+h)*48 + w ] = f2b(acc[mb][dy][r]);
    }
  }
}

// ---------------- BN + relu + 3^3/3 maxpool + spatial-sum (bf16 in) ----------
__global__ __launch_bounds__(256) void pool64_kernel(
    const short* __restrict__ t2, const float* __restrict__ sums,
    const float* __restrict__ gamma, const float* __restrict__ beta,
    float* __restrict__ pooled)
{
  int b = blockIdx.z, c = blockIdx.y;
  int cell = blockIdx.x*blockDim.x + threadIdx.x;   // 0..4095
  int pd = cell>>8; int rr = cell&255; int phh = rr>>4; int pww = rr&15;
  float mu  = sums[2*c]  *(1.f/(float)NV);
  float var = sums[2*c+1]*(1.f/(float)NV) - mu*mu;
  float sc  = rsqrtf(var+EPSBN)*gamma[c];
  float sh  = beta[c] - mu*sc;
  const short* base = t2 + ((size_t)b*64+c)*SS;
  float mx = -1e30f;
  #pragma unroll
  for (int kd=0;kd<3;++kd)
  #pragma unroll
  for (int kh=0;kh<3;++kh)
  #pragma unroll
  for (int kw=0;kw<3;++kw){
    float v = b2f(base[((pd*3+kd)*48 + (phh*3+kh))*48 + (pww*3+kw)]);
    v = fmaxf(fmaf(v,sc,sh), 0.f);
    mx = fmaxf(mx, v);
  }
  __shared__ float r[256];
  r[threadIdx.x]=mx; __syncthreads();
  for (int o=128;o>0;o>>=1){
    if (threadIdx.x<o) r[threadIdx.x]+=r[threadIdx.x+o];
    __syncthreads();
  }
  if (threadIdx.x==0) atomicAdd(&pooled[b*64+c], r[0]);
}

// ---------------- FC head ----------------
__global__ void fc_kernel(const float* __restrict__ pooled,
                          const float* __restrict__ w_fc, const float* __restrict__ b_fc,
                          float* __restrict__ logits)
{
  int t = threadIdx.x;
  if (t < 40){
    int b = t/10, k = t - 10*(t/10);
    float a = b_fc[k];
    #pragma unroll 1
    for (int c=0;c<64;++c) a = fmaf(pooled[b*64+c]*(1.f/4096.f), w_fc[k*64+c], a);
    logits[b*10+k] = a;
  }
}

extern "C" void kernel_launch(void* const* d_in, const int* in_sizes, int n_in,
                              void* d_out, int out_size, void* d_ws, size_t ws_size,
                              hipStream_t stream)
{
  const float* x    = (const float*)d_in[0];
  const float* w_p  = (const float*)d_in[1];
  const float* b_p  = (const float*)d_in[2];
  const float* w_m  = (const float*)d_in[3];
  const float* b_m  = (const float*)d_in[4];
  const float* w_dc = (const float*)d_in[5];
  const float* g_d  = (const float*)d_in[6];
  const float* be_d = (const float*)d_in[7];
  const float* w_c1 = (const float*)d_in[8];
  const float* g1   = (const float*)d_in[9];
  const float* be1  = (const float*)d_in[10];
  const float* w_c2 = (const float*)d_in[11];
  const float* g2   = (const float*)d_in[12];
  const float* be2  = (const float*)d_in[13];
  const float* w_fc = (const float*)d_in[14];
  const float* b_fc = (const float*)d_in[15];

  float* out    = (float*)d_out;
  float* logits = out;                 // 40
  float* xxx    = out + 40;            // NV  (stage-2 raw y)
  float* p_out  = out + 40 + NV;       // NV*81

  // workspace layout
  float* ws     = (float*)d_ws;
  float* inp    = ws;                        // NV fp32
  float* stats  = inp + NV;                  // 128
  float* pooled = stats + 128;               // 256
  short* wbf    = (short*)(pooled + 256);    // 27*64*32 bf16
  short* wo2    = wbf + 27*64*32;            // 112*32 bf16
  float* xpad   = (float*)(wo2 + 112*32);    // 4*50^3 fp32
  short* h1bf   = (short*)(xpad + (size_t)BSZ*PS);   // 4*32*SS bf16
  short* t2bf   = h1bf + (size_t)4*32*SS;    // 4*64*SS bf16
  float* y1     = (float*)t2bf;              // NV fp32, aliases t2bf (dead before conv2)

  const int nblk = (NV + 255)/256;     // 1728
  const int pblk = (BSZ*PS + 255)/256;

  // weight repacks (independent)
  wconv_kernel<<<(27*64*32+255)/256,256,0,stream>>>(w_c2, wbf);
  woff2_kernel<<<(112*32+255)/256,256,0,stream>>>(w_p, b_p, w_m, b_m, wo2);

  // ---- deform stage 1 ----
  pad_kernel<<<pblk,256,0,stream>>>(x, xpad);
  deform3_kernel<false><<<1728,256,0,stream>>>(xpad, wo2, w_dc, y1, nullptr);
  hipMemsetAsync(stats, 0, 2*sizeof(float), stream);
  bn_stats_kernel<<<dim3(64,1),256,0,stream>>>(y1, 1, stats);
  bn_relu_kernel<<<nblk,256,0,stream>>>(y1, inp, stats, g_d, be_d, 1);

  // ---- deform stage 2 (writes xxx and p) ----
  pad_kernel<<<pblk,256,0,stream>>>(inp, xpad);
  deform3_kernel<true><<<1728,256,0,stream>>>(xpad, wo2, w_dc, xxx, p_out);
  hipMemsetAsync(stats, 0, 2*sizeof(float), stream);
  bn_stats_kernel<<<dim3(64,1),256,0,stream>>>(xxx, 1, stats);
  bn_relu_kernel<<<nblk,256,0,stream>>>(xxx, inp, stats, g_d, be_d, 1);

  // ---- conv1 (fp32 in, bf16 out) + BN + relu in place ----
  conv1_kernel<<<nblk,256,0,stream>>>(inp, w_c1, h1bf);
  hipMemsetAsync(stats, 0, 64*sizeof(float), stream);
  bn_stats_bf16<<<dim3(64,32),256,0,stream>>>(h1bf, 32, stats);
  {
    int nb8 = (int)(((size_t)BSZ*32*(SS/8) + 255)/256);
    bn_relu_bf16<<<nb8,256,0,stream>>>(h1bf, stats, g1, be1, 32);
  }

  // ---- conv2 via MFMA (all 64 channels), then BN stats + pool fused ----
  conv2_mfma<<<1728,256,0,stream>>>(h1bf, wbf, t2bf);
  hipMemsetAsync(stats, 0, 128*sizeof(float), stream);
  bn_stats_bf16<<<dim3(64,64),256,0,stream>>>(t2bf, 64, stats);
  hipMemsetAsync(pooled, 0, 256*sizeof(float), stream);
  pool64_kernel<<<dim3(16,64,BSZ),256,0,stream>>>(t2bf, stats, g2, be2, pooled);

  // ---- FC head ----
  fc_kernel<<<1,64,0,stream>>>(pooled, w_fc, b_fc, logits);
}